// Round 1
// baseline (4372.521 us; speedup 1.0000x reference)
//
#include <hip/hip_runtime.h>

// Problem constants (fixed-size problem)
#define NNODES 100000
#define NEDGES 1600000
#define IN_C   128
#define HID_C  128
#define OUT_C  64

// ---------------------------------------------------------------------------
// Index width handling: reference says int64, but JAX without x64 gives int32.
// Detect on device: int64 little-endian => every odd 32-bit word is 0.
// ---------------------------------------------------------------------------
__device__ __forceinline__ long long load_idx(const void* p, long long i, int is64) {
  return is64 ? ((const long long*)p)[i] : (long long)((const int*)p)[i];
}

__global__ void detect_idx_kernel(const void* eidx, int* flag) {
  if (threadIdx.x == 0 && blockIdx.x == 0) {
    const unsigned* w = (const unsigned*)eidx;
    int ok = 1;
    for (int j = 0; j < 64; ++j) if (w[2 * j + 1] != 0u) ok = 0;
    *flag = ok;
  }
}

// ---------------------------------------------------------------------------
// Degree = 1 + in-degree(dst); then dinv = rsqrt(deg) in place.
// ---------------------------------------------------------------------------
__global__ void init_deg_kernel(float* deg) {
  int i = blockIdx.x * 256 + threadIdx.x;
  if (i < NNODES) deg[i] = 1.0f;
}

__global__ void count_deg_kernel(const void* eidx, const int* flag, float* deg) {
  int e = blockIdx.x * 256 + threadIdx.x;
  if (e < NEDGES) {
    long long d = load_idx(eidx, (long long)NEDGES + e, *flag);
    unsafeAtomicAdd(&deg[d], 1.0f);
  }
}

__global__ void rsqrt_kernel(float* deg) {
  int i = blockIdx.x * 256 + threadIdx.x;
  if (i < NNODES) deg[i] = rsqrtf(deg[i]);
}

// ---------------------------------------------------------------------------
// Skinny GEMM: H[M,NOUT] = X[M,K] @ W[K,NOUT].  W staged in LDS.
// 256 threads: (NOUT/4) col-threads x (256/(NOUT/4)) row-threads, 4 rows each.
// ---------------------------------------------------------------------------
__device__ __forceinline__ float4 fma4(float s, float4 w, float4 a) {
  a.x = fmaf(s, w.x, a.x);
  a.y = fmaf(s, w.y, a.y);
  a.z = fmaf(s, w.z, a.z);
  a.w = fmaf(s, w.w, a.w);
  return a;
}

template <int K, int NOUT>
__global__ __launch_bounds__(256) void gemm_kernel(const float* __restrict__ X,
                                                   const float* __restrict__ Wm,
                                                   float* __restrict__ Hout, int M) {
  constexpr int RPT = 4;
  constexpr int CT = NOUT / 4;       // col-threads (32 or 16)
  constexpr int RT = 256 / CT;       // row-threads (8 or 16)
  constexpr int BROWS = RT * RPT;    // rows per block (32 or 64)

  __shared__ float Wl[K * NOUT];
  const int tid = threadIdx.x;
  for (int i = tid * 4; i < K * NOUT; i += 256 * 4)
    *(float4*)&Wl[i] = *(const float4*)&Wm[i];
  __syncthreads();

  const int ct = tid % CT;
  const int rt = tid / CT;
  const long long row0 = (long long)blockIdx.x * BROWS + (long long)rt * RPT;

  // Clamp OOB reads to last row (writes are guarded), keeps inner loop branch-free.
  const float* xr[RPT];
#pragma unroll
  for (int r = 0; r < RPT; ++r) {
    long long rr = row0 + r;
    if (rr > M - 1) rr = M - 1;
    xr[r] = X + rr * K;
  }

  float4 acc[RPT];
#pragma unroll
  for (int r = 0; r < RPT; ++r) acc[r] = make_float4(0.f, 0.f, 0.f, 0.f);

#pragma unroll 4
  for (int k = 0; k < K; k += 4) {
    float4 w0 = *(const float4*)&Wl[(k + 0) * NOUT + ct * 4];
    float4 w1 = *(const float4*)&Wl[(k + 1) * NOUT + ct * 4];
    float4 w2 = *(const float4*)&Wl[(k + 2) * NOUT + ct * 4];
    float4 w3 = *(const float4*)&Wl[(k + 3) * NOUT + ct * 4];
#pragma unroll
    for (int r = 0; r < RPT; ++r) {
      float4 xv = *(const float4*)(xr[r] + k);
      acc[r] = fma4(xv.x, w0, acc[r]);
      acc[r] = fma4(xv.y, w1, acc[r]);
      acc[r] = fma4(xv.z, w2, acc[r]);
      acc[r] = fma4(xv.w, w3, acc[r]);
    }
  }

#pragma unroll
  for (int r = 0; r < RPT; ++r) {
    long long rr = row0 + r;
    if (rr < M) *(float4*)&Hout[rr * NOUT + ct * 4] = acc[r];
  }
}

// ---------------------------------------------------------------------------
// Agg init: Agg[i,c] = H[i,c] * dinv[i]^2 + bias[c]   (self-loop + bias)
// ---------------------------------------------------------------------------
template <int C>
__global__ void init_agg_kernel(const float* __restrict__ H,
                                const float* __restrict__ dinv,
                                const float* __restrict__ bias,
                                float* __restrict__ Agg) {
  int gid = blockIdx.x * 256 + threadIdx.x;
  constexpr int TPN = C / 4;
  int i = gid / TPN;
  int c4 = (gid % TPN) * 4;
  if (i >= NNODES) return;
  float di = dinv[i];
  float s = di * di;
  long long base = (long long)i * C + c4;
  float4 h = *(const float4*)&H[base];
  float4 b = *(const float4*)&bias[c4];
  float4 o;
  o.x = fmaf(h.x, s, b.x);
  o.y = fmaf(h.y, s, b.y);
  o.z = fmaf(h.z, s, b.z);
  o.w = fmaf(h.w, s, b.w);
  *(float4*)&Agg[base] = o;
}

// ---------------------------------------------------------------------------
// Edge scatter: Agg[dst,c] += H[src,c] * dinv[src]*dinv[dst]
// C/4 threads per edge; float4 gather; 4 scalar hw f32 atomics.
// ---------------------------------------------------------------------------
template <int C>
__global__ void scatter_kernel(const void* eidx, const int* flag,
                               const float* __restrict__ dinv,
                               const float* __restrict__ H,
                               float* __restrict__ Agg) {
  constexpr int TPE = C / 4;
  long long gid = (long long)blockIdx.x * 256 + threadIdx.x;
  long long e = gid / TPE;
  int c4 = (int)(gid % TPE) * 4;
  if (e >= NEDGES) return;
  int is64 = *flag;
  long long s = load_idx(eidx, e, is64);
  long long d = load_idx(eidx, (long long)NEDGES + e, is64);
  float nrm = dinv[s] * dinv[d];
  float4 h = *(const float4*)&H[s * C + c4];
  float* a = &Agg[d * C + c4];
  unsafeAtomicAdd(a + 0, h.x * nrm);
  unsafeAtomicAdd(a + 1, h.y * nrm);
  unsafeAtomicAdd(a + 2, h.z * nrm);
  unsafeAtomicAdd(a + 3, h.w * nrm);
}

// ---------------------------------------------------------------------------
// In-place ReLU over N*HID_C floats
// ---------------------------------------------------------------------------
__global__ void relu_kernel(float* __restrict__ A) {
  int gid = blockIdx.x * 256 + threadIdx.x;
  if (gid >= NNODES * (HID_C / 4)) return;
  float4 v = *(float4*)&A[(long long)gid * 4];
  v.x = v.x > 0.f ? v.x : 0.f;
  v.y = v.y > 0.f ? v.y : 0.f;
  v.z = v.z > 0.f ? v.z : 0.f;
  v.w = v.w > 0.f ? v.w : 0.f;
  *(float4*)&A[(long long)gid * 4] = v;
}

// ---------------------------------------------------------------------------
// Launch
// ---------------------------------------------------------------------------
extern "C" void kernel_launch(void* const* d_in, const int* in_sizes, int n_in,
                              void* d_out, int out_size, void* d_ws, size_t ws_size,
                              hipStream_t stream) {
  const float* x = (const float*)d_in[0];
  const void* eidx = d_in[1];
  const float* W1 = (const float*)d_in[2];
  const float* b1 = (const float*)d_in[3];
  const float* W2 = (const float*)d_in[4];
  const float* b2 = (const float*)d_in[5];
  float* out = (float*)d_out;

  // Workspace layout (needs ~104 MB):
  //   [0, 400000)            deg -> dinv
  //   [409600, +4)           idx-width flag
  //   [524288, +51.2MB)      h1  (reused as h2, which needs only 25.6MB)
  //   [52428800, +51.2MB)    agg1 (becomes hidden after ReLU)
  char* ws = (char*)d_ws;
  float* deg = (float*)ws;
  int* flag = (int*)(ws + 409600);
  float* h1 = (float*)(ws + 524288);
  float* agg1 = (float*)(ws + 52428800);
  float* h2 = h1;  // reuse

  detect_idx_kernel<<<1, 64, 0, stream>>>(eidx, flag);

  init_deg_kernel<<<(NNODES + 255) / 256, 256, 0, stream>>>(deg);
  count_deg_kernel<<<(NEDGES + 255) / 256, 256, 0, stream>>>(eidx, flag, deg);
  rsqrt_kernel<<<(NNODES + 255) / 256, 256, 0, stream>>>(deg);
  const float* dinv = deg;

  // Layer 1
  gemm_kernel<IN_C, HID_C><<<(NNODES + 31) / 32, 256, 0, stream>>>(x, W1, h1, NNODES);
  init_agg_kernel<HID_C><<<(NNODES * (HID_C / 4) + 255) / 256, 256, 0, stream>>>(h1, dinv, b1, agg1);
  scatter_kernel<HID_C><<<(int)(((long long)NEDGES * (HID_C / 4) + 255) / 256), 256, 0, stream>>>(
      eidx, flag, dinv, h1, agg1);
  relu_kernel<<<(NNODES * (HID_C / 4) + 255) / 256, 256, 0, stream>>>(agg1);

  // Layer 2 (hidden = agg1)
  gemm_kernel<HID_C, OUT_C><<<(NNODES + 63) / 64, 256, 0, stream>>>(agg1, W2, h2, NNODES);
  init_agg_kernel<OUT_C><<<(NNODES * (OUT_C / 4) + 255) / 256, 256, 0, stream>>>(h2, dinv, b2, out);
  scatter_kernel<OUT_C><<<(int)(((long long)NEDGES * (OUT_C / 4) + 255) / 256), 256, 0, stream>>>(
      eidx, flag, dinv, h2, out);
}

// Round 2
// 870.413 us; speedup vs baseline: 5.0235x; 5.0235x over previous
//
#include <hip/hip_runtime.h>

// Problem constants (fixed-size problem)
#define NNODES 100000
#define NEDGES 1600000
#define IN_C   128
#define HID_C  128
#define OUT_C  64

// ---------------------------------------------------------------------------
// Index width handling: reference says int64, but JAX without x64 gives int32.
// Detect on device: int64 little-endian => every odd 32-bit word is 0.
// ---------------------------------------------------------------------------
__device__ __forceinline__ long long load_idx(const void* p, long long i, int is64) {
  return is64 ? ((const long long*)p)[i] : (long long)((const int*)p)[i];
}

__global__ void detect_idx_kernel(const void* eidx, int* flag) {
  if (threadIdx.x == 0 && blockIdx.x == 0) {
    const unsigned* w = (const unsigned*)eidx;
    int ok = 1;
    for (int j = 0; j < 64; ++j) if (w[2 * j + 1] != 0u) ok = 0;
    *flag = ok;
  }
}

__device__ __forceinline__ float4 fma4(float s, float4 w, float4 a) {
  a.x = fmaf(s, w.x, a.x);
  a.y = fmaf(s, w.y, a.y);
  a.z = fmaf(s, w.z, a.z);
  a.w = fmaf(s, w.w, a.w);
  return a;
}

// ===========================================================================
// MAIN PATH: CSR build + gather aggregation (no float atomics)
// ===========================================================================

__global__ void zero_int_kernel(int* p, int n) {
  int i = blockIdx.x * 256 + threadIdx.x;
  if (i < n) p[i] = 0;
}

// in-degree histogram (int) into cursor[]
__global__ void count_deg_int_kernel(const void* eidx, const int* flag, int* cnt) {
  int e = blockIdx.x * 256 + threadIdx.x;
  if (e < NEDGES) {
    int is64 = *flag;
    long long d = load_idx(eidx, (long long)NEDGES + e, is64);
    atomicAdd(&cnt[(int)d], 1);
  }
}

// Single-block exclusive scan of cnt[NNODES] -> row_start, copy into cursor,
// and dinv[i] = rsqrt(cnt[i]+1). cnt aliases cursor (counts in, row_start out).
__global__ __launch_bounds__(1024) void scan_kernel(int* cursor, int* row_start,
                                                    float* dinv) {
  __shared__ int sums[1024];
  const int t = threadIdx.x;
  const int CHUNK = (NNODES + 1023) / 1024;  // 98
  const int beg = t * CHUNK;
  const int end = min(beg + CHUNK, NNODES);

  int own = 0;
  for (int i = beg; i < end; ++i) own += cursor[i];
  sums[t] = own;
  __syncthreads();
  // Hillis-Steele inclusive scan over 1024 partials
  for (int off = 1; off < 1024; off <<= 1) {
    int other = (t >= off) ? sums[t - off] : 0;
    __syncthreads();
    sums[t] += other;
    __syncthreads();
  }
  int run = sums[t] - own;  // exclusive base for this thread's chunk
  for (int i = beg; i < end; ++i) {
    int c = cursor[i];
    row_start[i] = run;
    cursor[i] = run;  // fill-cursor starts at row_start
    dinv[i] = rsqrtf((float)(c + 1));
    run += c;
  }
  if (t == 1023) row_start[NNODES] = NEDGES;
}

// Bucket edges by dst: csr_src[atomicAdd(cursor[d])] = s
__global__ void fill_csr_kernel(const void* eidx, const int* flag,
                                int* cursor, int* csr_src) {
  int e = blockIdx.x * 256 + threadIdx.x;
  if (e < NEDGES) {
    int is64 = *flag;
    int s = (int)load_idx(eidx, e, is64);
    int d = (int)load_idx(eidx, (long long)NEDGES + e, is64);
    int pos = atomicAdd(&cursor[d], 1);
    csr_src[pos] = s;
  }
}

// Gather aggregation: Out[i] = relu?( H[i]*dinv[i]^2 + bias
//                                     + sum_j H[csr_src[j]]*dinv[src]*dinv[i] )
template <int C, bool RELU>
__global__ __launch_bounds__(256) void gather_kernel(const int* __restrict__ row_start,
                                                     const int* __restrict__ csr_src,
                                                     const float* __restrict__ dinv,
                                                     const float* __restrict__ H,
                                                     const float* __restrict__ bias,
                                                     float* __restrict__ Out) {
  constexpr int TPN = C / 4;
  int gid = blockIdx.x * 256 + threadIdx.x;
  int i = gid / TPN;
  int c4 = (gid % TPN) * 4;
  if (i >= NNODES) return;

  float di = dinv[i];
  float4 b = *(const float4*)&bias[c4];
  float4 h = *(const float4*)&H[(long long)i * C + c4];
  float s2 = di * di;
  float4 acc;
  acc.x = fmaf(h.x, s2, b.x);
  acc.y = fmaf(h.y, s2, b.y);
  acc.z = fmaf(h.z, s2, b.z);
  acc.w = fmaf(h.w, s2, b.w);

  int beg = row_start[i];
  int end = row_start[i + 1];
  for (int j = beg; j < end; ++j) {
    int s = csr_src[j];
    float w = dinv[s] * di;
    float4 hv = *(const float4*)&H[(long long)s * C + c4];
    acc = fma4(w, hv, acc);
  }
  if (RELU) {
    acc.x = acc.x > 0.f ? acc.x : 0.f;
    acc.y = acc.y > 0.f ? acc.y : 0.f;
    acc.z = acc.z > 0.f ? acc.z : 0.f;
    acc.w = acc.w > 0.f ? acc.w : 0.f;
  }
  *(float4*)&Out[(long long)i * C + c4] = acc;
}

// ===========================================================================
// Shared: skinny GEMM, W staged in LDS
// ===========================================================================
template <int K, int NOUT>
__global__ __launch_bounds__(256) void gemm_kernel(const float* __restrict__ X,
                                                   const float* __restrict__ Wm,
                                                   float* __restrict__ Hout, int M) {
  constexpr int RPT = 4;
  constexpr int CT = NOUT / 4;       // col-threads (32 or 16)
  constexpr int RT = 256 / CT;       // row-threads (8 or 16)
  constexpr int BROWS = RT * RPT;    // rows per block (32 or 64)

  __shared__ float Wl[K * NOUT];
  const int tid = threadIdx.x;
  for (int i = tid * 4; i < K * NOUT; i += 256 * 4)
    *(float4*)&Wl[i] = *(const float4*)&Wm[i];
  __syncthreads();

  const int ct = tid % CT;
  const int rt = tid / CT;
  const long long row0 = (long long)blockIdx.x * BROWS + (long long)rt * RPT;

  const float* xr[RPT];
#pragma unroll
  for (int r = 0; r < RPT; ++r) {
    long long rr = row0 + r;
    if (rr > M - 1) rr = M - 1;
    xr[r] = X + rr * K;
  }

  float4 acc[RPT];
#pragma unroll
  for (int r = 0; r < RPT; ++r) acc[r] = make_float4(0.f, 0.f, 0.f, 0.f);

#pragma unroll 4
  for (int k = 0; k < K; k += 4) {
    float4 w0 = *(const float4*)&Wl[(k + 0) * NOUT + ct * 4];
    float4 w1 = *(const float4*)&Wl[(k + 1) * NOUT + ct * 4];
    float4 w2 = *(const float4*)&Wl[(k + 2) * NOUT + ct * 4];
    float4 w3 = *(const float4*)&Wl[(k + 3) * NOUT + ct * 4];
#pragma unroll
    for (int r = 0; r < RPT; ++r) {
      float4 xv = *(const float4*)(xr[r] + k);
      acc[r] = fma4(xv.x, w0, acc[r]);
      acc[r] = fma4(xv.y, w1, acc[r]);
      acc[r] = fma4(xv.z, w2, acc[r]);
      acc[r] = fma4(xv.w, w3, acc[r]);
    }
  }

#pragma unroll
  for (int r = 0; r < RPT; ++r) {
    long long rr = row0 + r;
    if (rr < M) *(float4*)&Hout[rr * NOUT + ct * 4] = acc[r];
  }
}

// ===========================================================================
// FALLBACK PATH (small ws): round-1 atomic scatter
// ===========================================================================
__global__ void init_deg_kernel(float* deg) {
  int i = blockIdx.x * 256 + threadIdx.x;
  if (i < NNODES) deg[i] = 1.0f;
}

__global__ void count_deg_kernel(const void* eidx, const int* flag, float* deg) {
  int e = blockIdx.x * 256 + threadIdx.x;
  if (e < NEDGES) {
    long long d = load_idx(eidx, (long long)NEDGES + e, *flag);
    unsafeAtomicAdd(&deg[d], 1.0f);
  }
}

__global__ void rsqrt_kernel(float* deg) {
  int i = blockIdx.x * 256 + threadIdx.x;
  if (i < NNODES) deg[i] = rsqrtf(deg[i]);
}

template <int C>
__global__ void init_agg_kernel(const float* __restrict__ H,
                                const float* __restrict__ dinv,
                                const float* __restrict__ bias,
                                float* __restrict__ Agg) {
  int gid = blockIdx.x * 256 + threadIdx.x;
  constexpr int TPN = C / 4;
  int i = gid / TPN;
  int c4 = (gid % TPN) * 4;
  if (i >= NNODES) return;
  float di = dinv[i];
  float s = di * di;
  long long base = (long long)i * C + c4;
  float4 h = *(const float4*)&H[base];
  float4 b = *(const float4*)&bias[c4];
  float4 o;
  o.x = fmaf(h.x, s, b.x);
  o.y = fmaf(h.y, s, b.y);
  o.z = fmaf(h.z, s, b.z);
  o.w = fmaf(h.w, s, b.w);
  *(float4*)&Agg[base] = o;
}

template <int C>
__global__ void scatter_kernel(const void* eidx, const int* flag,
                               const float* __restrict__ dinv,
                               const float* __restrict__ H,
                               float* __restrict__ Agg) {
  constexpr int TPE = C / 4;
  long long gid = (long long)blockIdx.x * 256 + threadIdx.x;
  long long e = gid / TPE;
  int c4 = (int)(gid % TPE) * 4;
  if (e >= NEDGES) return;
  int is64 = *flag;
  long long s = load_idx(eidx, e, is64);
  long long d = load_idx(eidx, (long long)NEDGES + e, is64);
  float nrm = dinv[s] * dinv[d];
  float4 h = *(const float4*)&H[s * C + c4];
  float* a = &Agg[d * C + c4];
  unsafeAtomicAdd(a + 0, h.x * nrm);
  unsafeAtomicAdd(a + 1, h.y * nrm);
  unsafeAtomicAdd(a + 2, h.z * nrm);
  unsafeAtomicAdd(a + 3, h.w * nrm);
}

__global__ void relu_kernel(float* __restrict__ A) {
  int gid = blockIdx.x * 256 + threadIdx.x;
  if (gid >= NNODES * (HID_C / 4)) return;
  float4 v = *(float4*)&A[(long long)gid * 4];
  v.x = v.x > 0.f ? v.x : 0.f;
  v.y = v.y > 0.f ? v.y : 0.f;
  v.z = v.z > 0.f ? v.z : 0.f;
  v.w = v.w > 0.f ? v.w : 0.f;
  *(float4*)&A[(long long)gid * 4] = v;
}

// ===========================================================================
// Launch
// ===========================================================================
extern "C" void kernel_launch(void* const* d_in, const int* in_sizes, int n_in,
                              void* d_out, int out_size, void* d_ws, size_t ws_size,
                              hipStream_t stream) {
  const float* x = (const float*)d_in[0];
  const void* eidx = d_in[1];
  const float* W1 = (const float*)d_in[2];
  const float* b1 = (const float*)d_in[3];
  const float* W2 = (const float*)d_in[4];
  const float* b2 = (const float*)d_in[5];
  float* out = (float*)d_out;
  char* ws = (char*)d_ws;

  // Main-path workspace layout (512B-aligned):
  //   dinv      @ 0          (400,000 B)
  //   row_start @ 401,408    (400,004 B)
  //   cursor    @ 802,816    (400,000 B)   [also the int histogram]
  //   flag      @ 1,203,200  (4 B)
  //   csr_src   @ 1,203,712  (6,400,000 B)
  //   h1        @ 7,604,224  (51,200,000 B)  [reused as h2 for layer 2]
  //   hidden    @ 58,804,224 (51,200,000 B)
  const size_t NEED = 110004224;

  if (ws_size >= NEED) {
    float* dinv = (float*)(ws + 0);
    int* row_start = (int*)(ws + 401408);
    int* cursor = (int*)(ws + 802816);
    int* flag = (int*)(ws + 1203200);
    int* csr_src = (int*)(ws + 1203712);
    float* h1 = (float*)(ws + 7604224);
    float* hidden = (float*)(ws + 58804224);
    float* h2 = h1;

    detect_idx_kernel<<<1, 64, 0, stream>>>(eidx, flag);
    zero_int_kernel<<<(NNODES + 255) / 256, 256, 0, stream>>>(cursor, NNODES);
    count_deg_int_kernel<<<(NEDGES + 255) / 256, 256, 0, stream>>>(eidx, flag, cursor);
    scan_kernel<<<1, 1024, 0, stream>>>(cursor, row_start, dinv);
    fill_csr_kernel<<<(NEDGES + 255) / 256, 256, 0, stream>>>(eidx, flag, cursor, csr_src);

    // Layer 1: h1 = x @ W1 ; hidden = relu(D^-1/2 (A+I) D^-1/2 h1 + b1)
    gemm_kernel<IN_C, HID_C><<<(NNODES + 31) / 32, 256, 0, stream>>>(x, W1, h1, NNODES);
    gather_kernel<HID_C, true>
        <<<(NNODES * (HID_C / 4) + 255) / 256, 256, 0, stream>>>(row_start, csr_src, dinv,
                                                                 h1, b1, hidden);
    // Layer 2
    gemm_kernel<HID_C, OUT_C><<<(NNODES + 63) / 64, 256, 0, stream>>>(hidden, W2, h2, NNODES);
    gather_kernel<OUT_C, false>
        <<<(NNODES * (OUT_C / 4) + 255) / 256, 256, 0, stream>>>(row_start, csr_src, dinv,
                                                                 h2, b2, out);
  } else {
    // Fallback: round-1 atomic-scatter path (~104 MB)
    float* deg = (float*)ws;
    int* flag = (int*)(ws + 409600);
    float* h1 = (float*)(ws + 524288);
    float* agg1 = (float*)(ws + 52428800);
    float* h2 = h1;

    detect_idx_kernel<<<1, 64, 0, stream>>>(eidx, flag);
    init_deg_kernel<<<(NNODES + 255) / 256, 256, 0, stream>>>(deg);
    count_deg_kernel<<<(NEDGES + 255) / 256, 256, 0, stream>>>(eidx, flag, deg);
    rsqrt_kernel<<<(NNODES + 255) / 256, 256, 0, stream>>>(deg);
    const float* dinv = deg;

    gemm_kernel<IN_C, HID_C><<<(NNODES + 31) / 32, 256, 0, stream>>>(x, W1, h1, NNODES);
    init_agg_kernel<HID_C><<<(NNODES * (HID_C / 4) + 255) / 256, 256, 0, stream>>>(h1, dinv, b1, agg1);
    scatter_kernel<HID_C><<<(int)(((long long)NEDGES * (HID_C / 4) + 255) / 256), 256, 0, stream>>>(
        eidx, flag, dinv, h1, agg1);
    relu_kernel<<<(NNODES * (HID_C / 4) + 255) / 256, 256, 0, stream>>>(agg1);

    gemm_kernel<HID_C, OUT_C><<<(NNODES + 63) / 64, 256, 0, stream>>>(agg1, W2, h2, NNODES);
    init_agg_kernel<OUT_C><<<(NNODES * (OUT_C / 4) + 255) / 256, 256, 0, stream>>>(h2, dinv, b2, out);
    scatter_kernel<OUT_C><<<(int)(((long long)NEDGES * (OUT_C / 4) + 255) / 256), 256, 0, stream>>>(
        eidx, flag, dinv, h2, out);
  }
}

// Round 3
// 602.909 us; speedup vs baseline: 7.2524x; 1.4437x over previous
//
#include <hip/hip_runtime.h>

// Problem constants (fixed-size problem)
#define NNODES 100000
#define NEDGES 1600000
#define IN_C   128
#define HID_C  128
#define OUT_C  64

#define SCAN_BLOCKS ((NNODES + 255) / 256)  // 391

// ---------------------------------------------------------------------------
// Index width handling: reference says int64, but JAX without x64 gives int32.
// Detect on device: int64 little-endian => every odd 32-bit word is 0.
// ---------------------------------------------------------------------------
__device__ __forceinline__ long long load_idx(const void* p, long long i, int is64) {
  return is64 ? ((const long long*)p)[i] : (long long)((const int*)p)[i];
}

__global__ void detect_idx_kernel(const void* eidx, int* flag) {
  // one wave: lane j checks odd word j
  const unsigned* w = (const unsigned*)eidx;
  int lane = threadIdx.x & 63;
  unsigned v = w[2 * lane + 1];
  unsigned long long bad = __ballot(v != 0u);
  if (lane == 0) *flag = (bad == 0ull) ? 1 : 0;
}

__device__ __forceinline__ float4 fma4(float s, float4 w, float4 a) {
  a.x = fmaf(s, w.x, a.x);
  a.y = fmaf(s, w.y, a.y);
  a.z = fmaf(s, w.z, a.z);
  a.w = fmaf(s, w.w, a.w);
  return a;
}

// ===========================================================================
// MAIN PATH: CSR build + gather aggregation (no float atomics)
// ===========================================================================

__global__ void zero_int_kernel(int* p, int n) {
  int i = blockIdx.x * 256 + threadIdx.x;
  if (i < n) p[i] = 0;
}

// in-degree histogram (int) into cnt[]
__global__ void count_deg_int_kernel(const void* eidx, const int* flag, int* cnt) {
  int e = blockIdx.x * 256 + threadIdx.x;
  if (e < NEDGES) {
    int is64 = *flag;
    long long d = load_idx(eidx, (long long)NEDGES + e, is64);
    atomicAdd(&cnt[(int)d], 1);
  }
}

// --- Parallel 3-phase exclusive scan of cnt[NNODES] ---
// Phase A: per-block (256 elems) sums -> partial[b]
__global__ __launch_bounds__(256) void scan_partial_kernel(const int* __restrict__ cnt,
                                                           int* __restrict__ partial) {
  __shared__ int red[256];
  int t = threadIdx.x;
  int i = blockIdx.x * 256 + t;
  int v = (i < NNODES) ? cnt[i] : 0;
  red[t] = v;
  __syncthreads();
#pragma unroll
  for (int off = 128; off > 0; off >>= 1) {
    if (t < off) red[t] += red[t + off];
    __syncthreads();
  }
  if (t == 0) partial[blockIdx.x] = red[0];
}

// Phase B: single block scans the 391 partials (exclusive)
__global__ __launch_bounds__(512) void scan_base_kernel(int* __restrict__ partial) {
  __shared__ int s[512];
  int t = threadIdx.x;
  int v = (t < SCAN_BLOCKS) ? partial[t] : 0;
  s[t] = v;
  __syncthreads();
  for (int off = 1; off < 512; off <<= 1) {
    int other = (t >= off) ? s[t - off] : 0;
    __syncthreads();
    s[t] += other;
    __syncthreads();
  }
  if (t < SCAN_BLOCKS) partial[t] = s[t] - v;  // exclusive base
}

// Phase C: block-local exclusive scan + base; write row_start, cursor, dinv
__global__ __launch_bounds__(256) void scan_final_kernel(const int* __restrict__ cnt_in,
                                                         const int* __restrict__ partial,
                                                         int* __restrict__ row_start,
                                                         int* __restrict__ cursor,
                                                         float* __restrict__ dinv) {
  __shared__ int s[256];
  int t = threadIdx.x;
  int i = blockIdx.x * 256 + t;
  int c = (i < NNODES) ? cnt_in[i] : 0;
  s[t] = c;
  __syncthreads();
  int acc = c;
  for (int off = 1; off < 256; off <<= 1) {
    int other = (t >= off) ? s[t - off] : 0;
    __syncthreads();
    acc += other;
    s[t] = acc;
    __syncthreads();
  }
  if (i < NNODES) {
    int rs = partial[blockIdx.x] + acc - c;  // exclusive
    row_start[i] = rs;
    cursor[i] = rs;
    dinv[i] = rsqrtf((float)(c + 1));
    if (i == NNODES - 1) row_start[NNODES] = NEDGES;
  }
}

// Bucket edges by dst: csr_src[atomicAdd(cursor[d])] = s
__global__ void fill_csr_kernel(const void* eidx, const int* flag,
                                int* cursor, int* csr_src) {
  int e = blockIdx.x * 256 + threadIdx.x;
  if (e < NEDGES) {
    int is64 = *flag;
    int s = (int)load_idx(eidx, e, is64);
    int d = (int)load_idx(eidx, (long long)NEDGES + e, is64);
    int pos = atomicAdd(&cursor[d], 1);
    csr_src[pos] = s;
  }
}

// Gather aggregation: Out[i] = relu?( H[i]*dinv[i]^2 + bias
//                                     + sum_j H[csr_src[j]]*dinv[src]*dinv[i] )
template <int C, bool RELU>
__global__ __launch_bounds__(256) void gather_kernel(const int* __restrict__ row_start,
                                                     const int* __restrict__ csr_src,
                                                     const float* __restrict__ dinv,
                                                     const float* __restrict__ H,
                                                     const float* __restrict__ bias,
                                                     float* __restrict__ Out) {
  constexpr int TPN = C / 4;
  int gid = blockIdx.x * 256 + threadIdx.x;
  int i = gid / TPN;
  int c4 = (gid % TPN) * 4;
  if (i >= NNODES) return;

  float di = dinv[i];
  float4 b = *(const float4*)&bias[c4];
  float4 h = *(const float4*)&H[(long long)i * C + c4];
  float s2 = di * di;
  float4 acc;
  acc.x = fmaf(h.x, s2, b.x);
  acc.y = fmaf(h.y, s2, b.y);
  acc.z = fmaf(h.z, s2, b.z);
  acc.w = fmaf(h.w, s2, b.w);

  int beg = row_start[i];
  int end = row_start[i + 1];
  for (int j = beg; j < end; ++j) {
    int s = csr_src[j];
    float w = dinv[s] * di;
    float4 hv = *(const float4*)&H[(long long)s * C + c4];
    acc = fma4(w, hv, acc);
  }
  if (RELU) {
    acc.x = acc.x > 0.f ? acc.x : 0.f;
    acc.y = acc.y > 0.f ? acc.y : 0.f;
    acc.z = acc.z > 0.f ? acc.z : 0.f;
    acc.w = acc.w > 0.f ? acc.w : 0.f;
  }
  *(float4*)&Out[(long long)i * C + c4] = acc;
}

// ===========================================================================
// Shared: skinny GEMM, W staged in LDS
// ===========================================================================
template <int K, int NOUT>
__global__ __launch_bounds__(256) void gemm_kernel(const float* __restrict__ X,
                                                   const float* __restrict__ Wm,
                                                   float* __restrict__ Hout, int M) {
  constexpr int RPT = 4;
  constexpr int CT = NOUT / 4;       // col-threads (32 or 16)
  constexpr int RT = 256 / CT;       // row-threads (8 or 16)
  constexpr int BROWS = RT * RPT;    // rows per block (32 or 64)

  __shared__ float Wl[K * NOUT];
  const int tid = threadIdx.x;
  for (int i = tid * 4; i < K * NOUT; i += 256 * 4)
    *(float4*)&Wl[i] = *(const float4*)&Wm[i];
  __syncthreads();

  const int ct = tid % CT;
  const int rt = tid / CT;
  const long long row0 = (long long)blockIdx.x * BROWS + (long long)rt * RPT;

  const float* xr[RPT];
#pragma unroll
  for (int r = 0; r < RPT; ++r) {
    long long rr = row0 + r;
    if (rr > M - 1) rr = M - 1;
    xr[r] = X + rr * K;
  }

  float4 acc[RPT];
#pragma unroll
  for (int r = 0; r < RPT; ++r) acc[r] = make_float4(0.f, 0.f, 0.f, 0.f);

#pragma unroll 4
  for (int k = 0; k < K; k += 4) {
    float4 w0 = *(const float4*)&Wl[(k + 0) * NOUT + ct * 4];
    float4 w1 = *(const float4*)&Wl[(k + 1) * NOUT + ct * 4];
    float4 w2 = *(const float4*)&Wl[(k + 2) * NOUT + ct * 4];
    float4 w3 = *(const float4*)&Wl[(k + 3) * NOUT + ct * 4];
#pragma unroll
    for (int r = 0; r < RPT; ++r) {
      float4 xv = *(const float4*)(xr[r] + k);
      acc[r] = fma4(xv.x, w0, acc[r]);
      acc[r] = fma4(xv.y, w1, acc[r]);
      acc[r] = fma4(xv.z, w2, acc[r]);
      acc[r] = fma4(xv.w, w3, acc[r]);
    }
  }

#pragma unroll
  for (int r = 0; r < RPT; ++r) {
    long long rr = row0 + r;
    if (rr < M) *(float4*)&Hout[rr * NOUT + ct * 4] = acc[r];
  }
}

// ===========================================================================
// FALLBACK PATH (small ws): round-1 atomic scatter
// ===========================================================================
__global__ void init_deg_kernel(float* deg) {
  int i = blockIdx.x * 256 + threadIdx.x;
  if (i < NNODES) deg[i] = 1.0f;
}

__global__ void count_deg_kernel(const void* eidx, const int* flag, float* deg) {
  int e = blockIdx.x * 256 + threadIdx.x;
  if (e < NEDGES) {
    long long d = load_idx(eidx, (long long)NEDGES + e, *flag);
    unsafeAtomicAdd(&deg[d], 1.0f);
  }
}

__global__ void rsqrt_kernel(float* deg) {
  int i = blockIdx.x * 256 + threadIdx.x;
  if (i < NNODES) deg[i] = rsqrtf(deg[i]);
}

template <int C>
__global__ void init_agg_kernel(const float* __restrict__ H,
                                const float* __restrict__ dinv,
                                const float* __restrict__ bias,
                                float* __restrict__ Agg) {
  int gid = blockIdx.x * 256 + threadIdx.x;
  constexpr int TPN = C / 4;
  int i = gid / TPN;
  int c4 = (gid % TPN) * 4;
  if (i >= NNODES) return;
  float di = dinv[i];
  float s = di * di;
  long long base = (long long)i * C + c4;
  float4 h = *(const float4*)&H[base];
  float4 b = *(const float4*)&bias[c4];
  float4 o;
  o.x = fmaf(h.x, s, b.x);
  o.y = fmaf(h.y, s, b.y);
  o.z = fmaf(h.z, s, b.z);
  o.w = fmaf(h.w, s, b.w);
  *(float4*)&Agg[base] = o;
}

template <int C>
__global__ void scatter_kernel(const void* eidx, const int* flag,
                               const float* __restrict__ dinv,
                               const float* __restrict__ H,
                               float* __restrict__ Agg) {
  constexpr int TPE = C / 4;
  long long gid = (long long)blockIdx.x * 256 + threadIdx.x;
  long long e = gid / TPE;
  int c4 = (int)(gid % TPE) * 4;
  if (e >= NEDGES) return;
  int is64 = *flag;
  long long s = load_idx(eidx, e, is64);
  long long d = load_idx(eidx, (long long)NEDGES + e, is64);
  float nrm = dinv[s] * dinv[d];
  float4 h = *(const float4*)&H[s * C + c4];
  float* a = &Agg[d * C + c4];
  unsafeAtomicAdd(a + 0, h.x * nrm);
  unsafeAtomicAdd(a + 1, h.y * nrm);
  unsafeAtomicAdd(a + 2, h.z * nrm);
  unsafeAtomicAdd(a + 3, h.w * nrm);
}

__global__ void relu_kernel(float* __restrict__ A) {
  int gid = blockIdx.x * 256 + threadIdx.x;
  if (gid >= NNODES * (HID_C / 4)) return;
  float4 v = *(float4*)&A[(long long)gid * 4];
  v.x = v.x > 0.f ? v.x : 0.f;
  v.y = v.y > 0.f ? v.y : 0.f;
  v.z = v.z > 0.f ? v.z : 0.f;
  v.w = v.w > 0.f ? v.w : 0.f;
  *(float4*)&A[(long long)gid * 4] = v;
}

// ===========================================================================
// Launch
// ===========================================================================
extern "C" void kernel_launch(void* const* d_in, const int* in_sizes, int n_in,
                              void* d_out, int out_size, void* d_ws, size_t ws_size,
                              hipStream_t stream) {
  const float* x = (const float*)d_in[0];
  const void* eidx = d_in[1];
  const float* W1 = (const float*)d_in[2];
  const float* b1 = (const float*)d_in[3];
  const float* W2 = (const float*)d_in[4];
  const float* b2 = (const float*)d_in[5];
  float* out = (float*)d_out;
  char* ws = (char*)d_ws;

  // Main-path workspace layout (512B-aligned):
  //   dinv      @ 0          (400,000 B)
  //   row_start @ 401,408    (400,004 B)
  //   cursor    @ 802,816    (400,000 B)   [histogram in, fill-cursor out]
  //   flag      @ 1,203,200  (4 B)
  //   partial   @ 1,203,712  (1,564 B)     (scan block bases)
  //   csr_src   @ 1,206,272  (6,400,000 B)
  //   h1        @ 7,606,784  (51,200,000 B)  [reused as h2 for layer 2]
  //   hidden    @ 58,806,784 (51,200,000 B)
  const size_t NEED = 110006784;

  if (ws_size >= NEED) {
    float* dinv = (float*)(ws + 0);
    int* row_start = (int*)(ws + 401408);
    int* cursor = (int*)(ws + 802816);
    int* flag = (int*)(ws + 1203200);
    int* partial = (int*)(ws + 1203712);
    int* csr_src = (int*)(ws + 1206272);
    float* h1 = (float*)(ws + 7606784);
    float* hidden = (float*)(ws + 58806784);
    float* h2 = h1;

    detect_idx_kernel<<<1, 64, 0, stream>>>(eidx, flag);
    zero_int_kernel<<<(NNODES + 255) / 256, 256, 0, stream>>>(cursor, NNODES);
    count_deg_int_kernel<<<(NEDGES + 255) / 256, 256, 0, stream>>>(eidx, flag, cursor);
    // parallel 3-phase scan (cursor holds counts)
    scan_partial_kernel<<<SCAN_BLOCKS, 256, 0, stream>>>(cursor, partial);
    scan_base_kernel<<<1, 512, 0, stream>>>(partial);
    scan_final_kernel<<<SCAN_BLOCKS, 256, 0, stream>>>(cursor, partial, row_start, cursor, dinv);
    fill_csr_kernel<<<(NEDGES + 255) / 256, 256, 0, stream>>>(eidx, flag, cursor, csr_src);

    // Layer 1: h1 = x @ W1 ; hidden = relu(D^-1/2 (A+I) D^-1/2 h1 + b1)
    gemm_kernel<IN_C, HID_C><<<(NNODES + 31) / 32, 256, 0, stream>>>(x, W1, h1, NNODES);
    gather_kernel<HID_C, true>
        <<<(NNODES * (HID_C / 4) + 255) / 256, 256, 0, stream>>>(row_start, csr_src, dinv,
                                                                 h1, b1, hidden);
    // Layer 2
    gemm_kernel<HID_C, OUT_C><<<(NNODES + 63) / 64, 256, 0, stream>>>(hidden, W2, h2, NNODES);
    gather_kernel<OUT_C, false>
        <<<(NNODES * (OUT_C / 4) + 255) / 256, 256, 0, stream>>>(row_start, csr_src, dinv,
                                                                 h2, b2, out);
  } else {
    // Fallback: round-1 atomic-scatter path (~104 MB)
    float* deg = (float*)ws;
    int* flag = (int*)(ws + 409600);
    float* h1 = (float*)(ws + 524288);
    float* agg1 = (float*)(ws + 52428800);
    float* h2 = h1;

    detect_idx_kernel<<<1, 64, 0, stream>>>(eidx, flag);
    init_deg_kernel<<<(NNODES + 255) / 256, 256, 0, stream>>>(deg);
    count_deg_kernel<<<(NEDGES + 255) / 256, 256, 0, stream>>>(eidx, flag, deg);
    rsqrt_kernel<<<(NNODES + 255) / 256, 256, 0, stream>>>(deg);
    const float* dinv = deg;

    gemm_kernel<IN_C, HID_C><<<(NNODES + 31) / 32, 256, 0, stream>>>(x, W1, h1, NNODES);
    init_agg_kernel<HID_C><<<(NNODES * (HID_C / 4) + 255) / 256, 256, 0, stream>>>(h1, dinv, b1, agg1);
    scatter_kernel<HID_C><<<(int)(((long long)NEDGES * (HID_C / 4) + 255) / 256), 256, 0, stream>>>(
        eidx, flag, dinv, h1, agg1);
    relu_kernel<<<(NNODES * (HID_C / 4) + 255) / 256, 256, 0, stream>>>(agg1);

    gemm_kernel<HID_C, OUT_C><<<(NNODES + 63) / 64, 256, 0, stream>>>(agg1, W2, h2, NNODES);
    init_agg_kernel<OUT_C><<<(NNODES * (OUT_C / 4) + 255) / 256, 256, 0, stream>>>(h2, dinv, b2, out);
    scatter_kernel<OUT_C><<<(int)(((long long)NEDGES * (OUT_C / 4) + 255) / 256), 256, 0, stream>>>(
        eidx, flag, dinv, h2, out);
  }
}

// Round 4
// 582.577 us; speedup vs baseline: 7.5055x; 1.0349x over previous
//
#include <hip/hip_runtime.h>

// Problem constants (fixed-size problem)
#define NNODES 100000
#define NEDGES 1600000
#define IN_C   128
#define HID_C  128
#define OUT_C  64

#define SCAN_BLOCKS ((NNODES + 255) / 256)  // 391

// ---------------------------------------------------------------------------
// Index width handling: reference says int64, but JAX without x64 gives int32.
// Detect on device: int64 little-endian => every odd 32-bit word is 0.
// ---------------------------------------------------------------------------
__device__ __forceinline__ long long load_idx(const void* p, long long i, int is64) {
  return is64 ? ((const long long*)p)[i] : (long long)((const int*)p)[i];
}

__global__ void detect_idx_kernel(const void* eidx, int* flag) {
  const unsigned* w = (const unsigned*)eidx;
  int lane = threadIdx.x & 63;
  unsigned v = w[2 * lane + 1];
  unsigned long long bad = __ballot(v != 0u);
  if (lane == 0) *flag = (bad == 0ull) ? 1 : 0;
}

__device__ __forceinline__ float4 fma4(float s, float4 w, float4 a) {
  a.x = fmaf(s, w.x, a.x);
  a.y = fmaf(s, w.y, a.y);
  a.z = fmaf(s, w.z, a.z);
  a.w = fmaf(s, w.w, a.w);
  return a;
}

__device__ __forceinline__ float4 add4(float4 a, float4 b) {
  a.x += b.x; a.y += b.y; a.z += b.z; a.w += b.w;
  return a;
}

// ===========================================================================
// MAIN PATH: CSR build + gather aggregation (no float atomics)
// ===========================================================================

__global__ void zero_int_kernel(int* p, int n) {
  int i = blockIdx.x * 256 + threadIdx.x;
  if (i < n) p[i] = 0;
}

__global__ void count_deg_int_kernel(const void* eidx, const int* flag, int* cnt) {
  int e = blockIdx.x * 256 + threadIdx.x;
  if (e < NEDGES) {
    int is64 = *flag;
    long long d = load_idx(eidx, (long long)NEDGES + e, is64);
    atomicAdd(&cnt[(int)d], 1);
  }
}

// --- Parallel 3-phase exclusive scan of cnt[NNODES] ---
__global__ __launch_bounds__(256) void scan_partial_kernel(const int* __restrict__ cnt,
                                                           int* __restrict__ partial) {
  __shared__ int red[256];
  int t = threadIdx.x;
  int i = blockIdx.x * 256 + t;
  int v = (i < NNODES) ? cnt[i] : 0;
  red[t] = v;
  __syncthreads();
#pragma unroll
  for (int off = 128; off > 0; off >>= 1) {
    if (t < off) red[t] += red[t + off];
    __syncthreads();
  }
  if (t == 0) partial[blockIdx.x] = red[0];
}

__global__ __launch_bounds__(512) void scan_base_kernel(int* __restrict__ partial) {
  __shared__ int s[512];
  int t = threadIdx.x;
  int v = (t < SCAN_BLOCKS) ? partial[t] : 0;
  s[t] = v;
  __syncthreads();
  for (int off = 1; off < 512; off <<= 1) {
    int other = (t >= off) ? s[t - off] : 0;
    __syncthreads();
    s[t] += other;
    __syncthreads();
  }
  if (t < SCAN_BLOCKS) partial[t] = s[t] - v;  // exclusive base
}

__global__ __launch_bounds__(256) void scan_final_kernel(const int* __restrict__ cnt_in,
                                                         const int* __restrict__ partial,
                                                         int* __restrict__ row_start,
                                                         int* __restrict__ cursor,
                                                         float* __restrict__ dinv) {
  __shared__ int s[256];
  int t = threadIdx.x;
  int i = blockIdx.x * 256 + t;
  int c = (i < NNODES) ? cnt_in[i] : 0;
  s[t] = c;
  __syncthreads();
  int acc = c;
  for (int off = 1; off < 256; off <<= 1) {
    int other = (t >= off) ? s[t - off] : 0;
    __syncthreads();
    acc += other;
    s[t] = acc;
    __syncthreads();
  }
  if (i < NNODES) {
    int rs = partial[blockIdx.x] + acc - c;  // exclusive
    row_start[i] = rs;
    cursor[i] = rs;
    dinv[i] = rsqrtf((float)(c + 1));
    if (i == NNODES - 1) row_start[NNODES] = NEDGES;
  }
}

__global__ void fill_csr_kernel(const void* eidx, const int* flag,
                                int* cursor, int* csr_src) {
  int e = blockIdx.x * 256 + threadIdx.x;
  if (e < NEDGES) {
    int is64 = *flag;
    int s = (int)load_idx(eidx, e, is64);
    int d = (int)load_idx(eidx, (long long)NEDGES + e, is64);
    int pos = atomicAdd(&cursor[d], 1);
    csr_src[pos] = s;
  }
}

// ---------------------------------------------------------------------------
// Gather aggregation over PRE-SCALED rows Hs[i] = h[i]*dinv[i]:
//   Out[i] = act( dinv[i] * (Hs[i] + sum_j Hs[csr_src[j]]) + bias )
// Per-edge chain is csr load -> row load -> add (no dinv[s], no weight FMA).
// 8-way unroll, 4 accumulator chains for MLP.
// ---------------------------------------------------------------------------
template <int C, bool RELU>
__global__ __launch_bounds__(256) void gather_kernel(const int* __restrict__ row_start,
                                                     const int* __restrict__ csr_src,
                                                     const float* __restrict__ dinv,
                                                     const float* __restrict__ Hs,
                                                     const float* __restrict__ bias,
                                                     float* __restrict__ Out) {
  constexpr int TPN = C / 4;
  int gid = blockIdx.x * 256 + threadIdx.x;
  int i = gid / TPN;
  int c4 = (gid % TPN) * 4;
  if (i >= NNODES) return;

  const float di = dinv[i];
  const int beg = row_start[i];
  const int end = row_start[i + 1];

  float4 a0 = *(const float4*)&Hs[(size_t)i * C + c4];  // self term (pre-scaled)
  float4 a1 = make_float4(0.f, 0.f, 0.f, 0.f);
  float4 a2 = make_float4(0.f, 0.f, 0.f, 0.f);
  float4 a3 = make_float4(0.f, 0.f, 0.f, 0.f);

  int j = beg;
  for (; j + 8 <= end; j += 8) {
    int s0 = csr_src[j + 0], s1 = csr_src[j + 1], s2 = csr_src[j + 2], s3 = csr_src[j + 3];
    int s4 = csr_src[j + 4], s5 = csr_src[j + 5], s6 = csr_src[j + 6], s7 = csr_src[j + 7];
    float4 h0 = *(const float4*)&Hs[(size_t)s0 * C + c4];
    float4 h1 = *(const float4*)&Hs[(size_t)s1 * C + c4];
    float4 h2 = *(const float4*)&Hs[(size_t)s2 * C + c4];
    float4 h3 = *(const float4*)&Hs[(size_t)s3 * C + c4];
    float4 h4 = *(const float4*)&Hs[(size_t)s4 * C + c4];
    float4 h5 = *(const float4*)&Hs[(size_t)s5 * C + c4];
    float4 h6 = *(const float4*)&Hs[(size_t)s6 * C + c4];
    float4 h7 = *(const float4*)&Hs[(size_t)s7 * C + c4];
    a0 = add4(a0, h0);
    a1 = add4(a1, h1);
    a2 = add4(a2, h2);
    a3 = add4(a3, h3);
    a0 = add4(a0, h4);
    a1 = add4(a1, h5);
    a2 = add4(a2, h6);
    a3 = add4(a3, h7);
  }
  for (; j + 2 <= end; j += 2) {
    int s0 = csr_src[j + 0], s1 = csr_src[j + 1];
    float4 h0 = *(const float4*)&Hs[(size_t)s0 * C + c4];
    float4 h1 = *(const float4*)&Hs[(size_t)s1 * C + c4];
    a0 = add4(a0, h0);
    a1 = add4(a1, h1);
  }
  if (j < end) {
    int s0 = csr_src[j];
    a0 = add4(a0, *(const float4*)&Hs[(size_t)s0 * C + c4]);
  }

  float4 sum = add4(add4(a0, a1), add4(a2, a3));
  float4 b = *(const float4*)&bias[c4];
  float4 o;
  o.x = fmaf(sum.x, di, b.x);
  o.y = fmaf(sum.y, di, b.y);
  o.z = fmaf(sum.z, di, b.z);
  o.w = fmaf(sum.w, di, b.w);
  if (RELU) {
    o.x = o.x > 0.f ? o.x : 0.f;
    o.y = o.y > 0.f ? o.y : 0.f;
    o.z = o.z > 0.f ? o.z : 0.f;
    o.w = o.w > 0.f ? o.w : 0.f;
  }
  *(float4*)&Out[(size_t)i * C + c4] = o;
}

// ===========================================================================
// Skinny GEMM, W staged in LDS. Optional per-row output scale (dinv) fused.
// ===========================================================================
template <int K, int NOUT, bool SCALE>
__global__ __launch_bounds__(256) void gemm_kernel(const float* __restrict__ X,
                                                   const float* __restrict__ Wm,
                                                   const float* __restrict__ scale,
                                                   float* __restrict__ Hout, int M) {
  constexpr int RPT = 4;
  constexpr int CT = NOUT / 4;       // col-threads (32 or 16)
  constexpr int RT = 256 / CT;       // row-threads (8 or 16)
  constexpr int BROWS = RT * RPT;    // rows per block (32 or 64)

  __shared__ float Wl[K * NOUT];
  const int tid = threadIdx.x;
  for (int i = tid * 4; i < K * NOUT; i += 256 * 4)
    *(float4*)&Wl[i] = *(const float4*)&Wm[i];
  __syncthreads();

  const int ct = tid % CT;
  const int rt = tid / CT;
  const long long row0 = (long long)blockIdx.x * BROWS + (long long)rt * RPT;

  const float* xr[RPT];
#pragma unroll
  for (int r = 0; r < RPT; ++r) {
    long long rr = row0 + r;
    if (rr > M - 1) rr = M - 1;
    xr[r] = X + rr * K;
  }

  float4 acc[RPT];
#pragma unroll
  for (int r = 0; r < RPT; ++r) acc[r] = make_float4(0.f, 0.f, 0.f, 0.f);

#pragma unroll 4
  for (int k = 0; k < K; k += 4) {
    float4 w0 = *(const float4*)&Wl[(k + 0) * NOUT + ct * 4];
    float4 w1 = *(const float4*)&Wl[(k + 1) * NOUT + ct * 4];
    float4 w2 = *(const float4*)&Wl[(k + 2) * NOUT + ct * 4];
    float4 w3 = *(const float4*)&Wl[(k + 3) * NOUT + ct * 4];
#pragma unroll
    for (int r = 0; r < RPT; ++r) {
      float4 xv = *(const float4*)(xr[r] + k);
      acc[r] = fma4(xv.x, w0, acc[r]);
      acc[r] = fma4(xv.y, w1, acc[r]);
      acc[r] = fma4(xv.z, w2, acc[r]);
      acc[r] = fma4(xv.w, w3, acc[r]);
    }
  }

#pragma unroll
  for (int r = 0; r < RPT; ++r) {
    long long rr = row0 + r;
    if (rr < M) {
      float4 v = acc[r];
      if (SCALE) {
        float s = scale[rr];
        v.x *= s; v.y *= s; v.z *= s; v.w *= s;
      }
      *(float4*)&Hout[rr * NOUT + ct * 4] = v;
    }
  }
}

// ===========================================================================
// FALLBACK PATH (small ws): round-1 atomic scatter
// ===========================================================================
__global__ void init_deg_kernel(float* deg) {
  int i = blockIdx.x * 256 + threadIdx.x;
  if (i < NNODES) deg[i] = 1.0f;
}

__global__ void count_deg_kernel(const void* eidx, const int* flag, float* deg) {
  int e = blockIdx.x * 256 + threadIdx.x;
  if (e < NEDGES) {
    long long d = load_idx(eidx, (long long)NEDGES + e, *flag);
    unsafeAtomicAdd(&deg[d], 1.0f);
  }
}

__global__ void rsqrt_kernel(float* deg) {
  int i = blockIdx.x * 256 + threadIdx.x;
  if (i < NNODES) deg[i] = rsqrtf(deg[i]);
}

template <int C>
__global__ void init_agg_kernel(const float* __restrict__ H,
                                const float* __restrict__ dinv,
                                const float* __restrict__ bias,
                                float* __restrict__ Agg) {
  int gid = blockIdx.x * 256 + threadIdx.x;
  constexpr int TPN = C / 4;
  int i = gid / TPN;
  int c4 = (gid % TPN) * 4;
  if (i >= NNODES) return;
  float di = dinv[i];
  float s = di * di;
  long long base = (long long)i * C + c4;
  float4 h = *(const float4*)&H[base];
  float4 b = *(const float4*)&bias[c4];
  float4 o;
  o.x = fmaf(h.x, s, b.x);
  o.y = fmaf(h.y, s, b.y);
  o.z = fmaf(h.z, s, b.z);
  o.w = fmaf(h.w, s, b.w);
  *(float4*)&Agg[base] = o;
}

template <int C>
__global__ void scatter_kernel(const void* eidx, const int* flag,
                               const float* __restrict__ dinv,
                               const float* __restrict__ H,
                               float* __restrict__ Agg) {
  constexpr int TPE = C / 4;
  long long gid = (long long)blockIdx.x * 256 + threadIdx.x;
  long long e = gid / TPE;
  int c4 = (int)(gid % TPE) * 4;
  if (e >= NEDGES) return;
  int is64 = *flag;
  long long s = load_idx(eidx, e, is64);
  long long d = load_idx(eidx, (long long)NEDGES + e, is64);
  float nrm = dinv[s] * dinv[d];
  float4 h = *(const float4*)&H[s * C + c4];
  float* a = &Agg[d * C + c4];
  unsafeAtomicAdd(a + 0, h.x * nrm);
  unsafeAtomicAdd(a + 1, h.y * nrm);
  unsafeAtomicAdd(a + 2, h.z * nrm);
  unsafeAtomicAdd(a + 3, h.w * nrm);
}

__global__ void relu_kernel(float* __restrict__ A) {
  int gid = blockIdx.x * 256 + threadIdx.x;
  if (gid >= NNODES * (HID_C / 4)) return;
  float4 v = *(float4*)&A[(long long)gid * 4];
  v.x = v.x > 0.f ? v.x : 0.f;
  v.y = v.y > 0.f ? v.y : 0.f;
  v.z = v.z > 0.f ? v.z : 0.f;
  v.w = v.w > 0.f ? v.w : 0.f;
  *(float4*)&A[(long long)gid * 4] = v;
}

// ===========================================================================
// Launch
// ===========================================================================
extern "C" void kernel_launch(void* const* d_in, const int* in_sizes, int n_in,
                              void* d_out, int out_size, void* d_ws, size_t ws_size,
                              hipStream_t stream) {
  const float* x = (const float*)d_in[0];
  const void* eidx = d_in[1];
  const float* W1 = (const float*)d_in[2];
  const float* b1 = (const float*)d_in[3];
  const float* W2 = (const float*)d_in[4];
  const float* b2 = (const float*)d_in[5];
  float* out = (float*)d_out;
  char* ws = (char*)d_ws;

  // Main-path workspace layout (512B-aligned):
  //   dinv      @ 0          (400,000 B)
  //   row_start @ 401,408    (400,004 B)
  //   cursor    @ 802,816    (400,000 B)   [histogram in, fill-cursor out]
  //   flag      @ 1,203,200  (4 B)
  //   partial   @ 1,203,712  (1,564 B)     (scan block bases)
  //   csr_src   @ 1,206,272  (6,400,000 B)
  //   h1        @ 7,606,784  (51,200,000 B)  [pre-scaled Hs; reused for layer 2]
  //   hidden    @ 58,806,784 (51,200,000 B)
  const size_t NEED = 110006784;

  if (ws_size >= NEED) {
    float* dinv = (float*)(ws + 0);
    int* row_start = (int*)(ws + 401408);
    int* cursor = (int*)(ws + 802816);
    int* flag = (int*)(ws + 1203200);
    int* partial = (int*)(ws + 1203712);
    int* csr_src = (int*)(ws + 1206272);
    float* h1 = (float*)(ws + 7606784);
    float* hidden = (float*)(ws + 58806784);
    float* h2 = h1;

    detect_idx_kernel<<<1, 64, 0, stream>>>(eidx, flag);
    zero_int_kernel<<<(NNODES + 255) / 256, 256, 0, stream>>>(cursor, NNODES);
    count_deg_int_kernel<<<(NEDGES + 255) / 256, 256, 0, stream>>>(eidx, flag, cursor);
    scan_partial_kernel<<<SCAN_BLOCKS, 256, 0, stream>>>(cursor, partial);
    scan_base_kernel<<<1, 512, 0, stream>>>(partial);
    scan_final_kernel<<<SCAN_BLOCKS, 256, 0, stream>>>(cursor, partial, row_start, cursor, dinv);
    fill_csr_kernel<<<(NEDGES + 255) / 256, 256, 0, stream>>>(eidx, flag, cursor, csr_src);

    // Layer 1: Hs1 = (x @ W1) * dinv[row] ; hidden = relu(di*(Hs1[i]+sum) + b1)
    gemm_kernel<IN_C, HID_C, true>
        <<<(NNODES + 31) / 32, 256, 0, stream>>>(x, W1, dinv, h1, NNODES);
    gather_kernel<HID_C, true>
        <<<(NNODES * (HID_C / 4) + 255) / 256, 256, 0, stream>>>(row_start, csr_src, dinv,
                                                                 h1, b1, hidden);
    // Layer 2: Hs2 = (hidden @ W2) * dinv[row] ; out = di*(Hs2[i]+sum) + b2
    gemm_kernel<HID_C, OUT_C, true>
        <<<(NNODES + 63) / 64, 256, 0, stream>>>(hidden, W2, dinv, h2, NNODES);
    gather_kernel<OUT_C, false>
        <<<(NNODES * (OUT_C / 4) + 255) / 256, 256, 0, stream>>>(row_start, csr_src, dinv,
                                                                 h2, b2, out);
  } else {
    // Fallback: round-1 atomic-scatter path (~104 MB)
    float* deg = (float*)ws;
    int* flag = (int*)(ws + 409600);
    float* h1 = (float*)(ws + 524288);
    float* agg1 = (float*)(ws + 52428800);
    float* h2 = h1;

    detect_idx_kernel<<<1, 64, 0, stream>>>(eidx, flag);
    init_deg_kernel<<<(NNODES + 255) / 256, 256, 0, stream>>>(deg);
    count_deg_kernel<<<(NEDGES + 255) / 256, 256, 0, stream>>>(eidx, flag, deg);
    rsqrt_kernel<<<(NNODES + 255) / 256, 256, 0, stream>>>(deg);
    const float* dinv = deg;

    gemm_kernel<IN_C, HID_C, false><<<(NNODES + 31) / 32, 256, 0, stream>>>(x, W1, nullptr, h1, NNODES);
    init_agg_kernel<HID_C><<<(NNODES * (HID_C / 4) + 255) / 256, 256, 0, stream>>>(h1, dinv, b1, agg1);
    scatter_kernel<HID_C><<<(int)(((long long)NEDGES * (HID_C / 4) + 255) / 256), 256, 0, stream>>>(
        eidx, flag, dinv, h1, agg1);
    relu_kernel<<<(NNODES * (HID_C / 4) + 255) / 256, 256, 0, stream>>>(agg1);

    gemm_kernel<HID_C, OUT_C, false><<<(NNODES + 63) / 64, 256, 0, stream>>>(agg1, W2, nullptr, h2, NNODES);
    init_agg_kernel<OUT_C><<<(NNODES * (OUT_C / 4) + 255) / 256, 256, 0, stream>>>(h2, dinv, b2, out);
    scatter_kernel<OUT_C><<<(int)(((long long)NEDGES * (OUT_C / 4) + 255) / 256), 256, 0, stream>>>(
        eidx, flag, dinv, h2, out);
  }
}

// Round 5
// 465.984 us; speedup vs baseline: 9.3834x; 1.2502x over previous
//
#include <hip/hip_runtime.h>
#include <hip/hip_fp16.h>

// Problem constants (fixed-size problem)
#define NNODES 100000
#define NEDGES 1600000
#define IN_C   128
#define HID_C  128
#define OUT_C  64

#define SCAN_BLOCKS ((NNODES + 255) / 256)  // 391
#define XCD_COUNT   8
#define XCD_NODES   ((NNODES + XCD_COUNT - 1) / XCD_COUNT)  // 12500
#define FILL_CHUNKS 80
#define EDGES_PER_CHUNK ((NEDGES + FILL_CHUNKS - 1) / FILL_CHUNKS)  // 20000

// ---------------------------------------------------------------------------
// Index width handling: reference says int64, but JAX without x64 gives int32.
// Detect on device: int64 little-endian => every odd 32-bit word is 0.
// ---------------------------------------------------------------------------
__device__ __forceinline__ long long load_idx(const void* p, long long i, int is64) {
  return is64 ? ((const long long*)p)[i] : (long long)((const int*)p)[i];
}

__global__ void detect_idx_kernel(const void* eidx, int* flag) {
  const unsigned* w = (const unsigned*)eidx;
  int lane = threadIdx.x & 63;
  unsigned v = w[2 * lane + 1];
  unsigned long long bad = __ballot(v != 0u);
  if (lane == 0) *flag = (bad == 0ull) ? 1 : 0;
}

__device__ __forceinline__ float4 fma4(float s, float4 w, float4 a) {
  a.x = fmaf(s, w.x, a.x);
  a.y = fmaf(s, w.y, a.y);
  a.z = fmaf(s, w.z, a.z);
  a.w = fmaf(s, w.w, a.w);
  return a;
}

// ===========================================================================
// CSR build
// ===========================================================================

__global__ void zero_int_kernel(int* p, int n) {
  int i = blockIdx.x * 256 + threadIdx.x;
  if (i < n) p[i] = 0;
}

// Fused: compress edge indices to int32 arrays + in-degree histogram.
__global__ void compress_count_kernel(const void* eidx, const int* flag,
                                      int* __restrict__ src32,
                                      int* __restrict__ dst32,
                                      int* __restrict__ cnt) {
  int e = blockIdx.x * 256 + threadIdx.x;
  if (e < NEDGES) {
    int is64 = *flag;
    int s = (int)load_idx(eidx, e, is64);
    int d = (int)load_idx(eidx, (long long)NEDGES + e, is64);
    src32[e] = s;
    dst32[e] = d;
    atomicAdd(&cnt[d], 1);
  }
}

// --- Parallel 3-phase exclusive scan of cnt[NNODES] ---
__global__ __launch_bounds__(256) void scan_partial_kernel(const int* __restrict__ cnt,
                                                           int* __restrict__ partial) {
  __shared__ int red[256];
  int t = threadIdx.x;
  int i = blockIdx.x * 256 + t;
  int v = (i < NNODES) ? cnt[i] : 0;
  red[t] = v;
  __syncthreads();
#pragma unroll
  for (int off = 128; off > 0; off >>= 1) {
    if (t < off) red[t] += red[t + off];
    __syncthreads();
  }
  if (t == 0) partial[blockIdx.x] = red[0];
}

__global__ __launch_bounds__(512) void scan_base_kernel(int* __restrict__ partial) {
  __shared__ int s[512];
  int t = threadIdx.x;
  int v = (t < SCAN_BLOCKS) ? partial[t] : 0;
  s[t] = v;
  __syncthreads();
  for (int off = 1; off < 512; off <<= 1) {
    int other = (t >= off) ? s[t - off] : 0;
    __syncthreads();
    s[t] += other;
    __syncthreads();
  }
  if (t < SCAN_BLOCKS) partial[t] = s[t] - v;  // exclusive base
}

__global__ __launch_bounds__(256) void scan_final_kernel(const int* __restrict__ cnt_in,
                                                         const int* __restrict__ partial,
                                                         int* __restrict__ row_start,
                                                         int* __restrict__ cursor,
                                                         float* __restrict__ dinv) {
  __shared__ int s[256];
  int t = threadIdx.x;
  int i = blockIdx.x * 256 + t;
  int c = (i < NNODES) ? cnt_in[i] : 0;
  s[t] = c;
  __syncthreads();
  int acc = c;
  for (int off = 1; off < 256; off <<= 1) {
    int other = (t >= off) ? s[t - off] : 0;
    __syncthreads();
    acc += other;
    s[t] = acc;
    __syncthreads();
  }
  if (i < NNODES) {
    int rs = partial[blockIdx.x] + acc - c;  // exclusive
    row_start[i] = rs;
    cursor[i] = rs;
    dinv[i] = rsqrtf((float)(c + 1));
    if (i == NNODES - 1) row_start[NNODES] = NEDGES;
  }
}

// XCD-partitioned CSR fill: block b (xcd = b%8) only handles dst in its
// 12.5K-node slice, so its csr_src/cursor stores stay in that XCD's L2.
// Each of the 80 edge-chunks is scanned by 8 blocks (one per XCD slice);
// the int32 dst/src arrays (12.8 MB) are L2/L3-cached across re-reads.
__global__ __launch_bounds__(256) void fill_csr_xcd_kernel(const int* __restrict__ src32,
                                                           const int* __restrict__ dst32,
                                                           int* __restrict__ cursor,
                                                           int* __restrict__ csr_src) {
  const int xcd = blockIdx.x & (XCD_COUNT - 1);
  const int chunk = blockIdx.x >> 3;
  const int lo = xcd * XCD_NODES;
  const int e_beg = chunk * EDGES_PER_CHUNK;
  const int e_end = min(e_beg + EDGES_PER_CHUNK, NEDGES);
  for (int e = e_beg + threadIdx.x; e < e_end; e += 256) {
    int d = dst32[e];
    int s = src32[e];
    if ((unsigned)(d - lo) < (unsigned)XCD_NODES) {
      int pos = atomicAdd(&cursor[d], 1);
      csr_src[pos] = s;
    }
  }
}

// ---------------------------------------------------------------------------
// Gather aggregation over PRE-SCALED fp16 rows Hs[i] = h[i]*dinv[i]:
//   Out[i] = act( dinv[i] * (Hs[i] + sum_j Hs[csr_src[j]]) + bias )   (fp32 out)
// 8 channels per thread (16 B loads), fp32 accumulate, 8-edge unroll,
// 4 accumulator chains.
// ---------------------------------------------------------------------------
struct F8 {
  float x0, x1, x2, x3, x4, x5, x6, x7;
};

__device__ __forceinline__ void add_h8(F8& a, const __half* p) {
  int4 r = *(const int4*)p;  // 8 halves
  const __half2* h = (const __half2*)&r;
  float2 f0 = __half22float2(h[0]);
  float2 f1 = __half22float2(h[1]);
  float2 f2 = __half22float2(h[2]);
  float2 f3 = __half22float2(h[3]);
  a.x0 += f0.x; a.x1 += f0.y; a.x2 += f1.x; a.x3 += f1.y;
  a.x4 += f2.x; a.x5 += f2.y; a.x6 += f3.x; a.x7 += f3.y;
}

template <int C, bool RELU>
__global__ __launch_bounds__(256) void gather_kernel(const int* __restrict__ row_start,
                                                     const int* __restrict__ csr_src,
                                                     const float* __restrict__ dinv,
                                                     const __half* __restrict__ Hs,
                                                     const float* __restrict__ bias,
                                                     float* __restrict__ Out) {
  constexpr int TPN = C / 8;  // threads per node (16 or 8)
  int gid = blockIdx.x * 256 + threadIdx.x;
  int i = gid / TPN;
  int c8 = (gid % TPN) * 8;
  if (i >= NNODES) return;

  const float di = dinv[i];
  const int beg = row_start[i];
  const int end = row_start[i + 1];

  F8 a0 = {}, a1 = {}, a2 = {}, a3 = {};
  add_h8(a0, &Hs[(size_t)i * C + c8]);  // self term (pre-scaled)

  int j = beg;
  for (; j + 8 <= end; j += 8) {
    int s0 = csr_src[j + 0], s1 = csr_src[j + 1], s2 = csr_src[j + 2], s3 = csr_src[j + 3];
    int s4 = csr_src[j + 4], s5 = csr_src[j + 5], s6 = csr_src[j + 6], s7 = csr_src[j + 7];
    add_h8(a0, &Hs[(size_t)s0 * C + c8]);
    add_h8(a1, &Hs[(size_t)s1 * C + c8]);
    add_h8(a2, &Hs[(size_t)s2 * C + c8]);
    add_h8(a3, &Hs[(size_t)s3 * C + c8]);
    add_h8(a0, &Hs[(size_t)s4 * C + c8]);
    add_h8(a1, &Hs[(size_t)s5 * C + c8]);
    add_h8(a2, &Hs[(size_t)s6 * C + c8]);
    add_h8(a3, &Hs[(size_t)s7 * C + c8]);
  }
  for (; j + 2 <= end; j += 2) {
    int s0 = csr_src[j + 0], s1 = csr_src[j + 1];
    add_h8(a0, &Hs[(size_t)s0 * C + c8]);
    add_h8(a1, &Hs[(size_t)s1 * C + c8]);
  }
  if (j < end) {
    add_h8(a0, &Hs[(size_t)csr_src[j] * C + c8]);
  }

  float s0 = a0.x0 + a1.x0 + a2.x0 + a3.x0;
  float s1 = a0.x1 + a1.x1 + a2.x1 + a3.x1;
  float s2 = a0.x2 + a1.x2 + a2.x2 + a3.x2;
  float s3 = a0.x3 + a1.x3 + a2.x3 + a3.x3;
  float s4 = a0.x4 + a1.x4 + a2.x4 + a3.x4;
  float s5 = a0.x5 + a1.x5 + a2.x5 + a3.x5;
  float s6 = a0.x6 + a1.x6 + a2.x6 + a3.x6;
  float s7 = a0.x7 + a1.x7 + a2.x7 + a3.x7;

  float4 b0 = *(const float4*)&bias[c8];
  float4 b1 = *(const float4*)&bias[c8 + 4];
  float4 o0, o1;
  o0.x = fmaf(s0, di, b0.x);
  o0.y = fmaf(s1, di, b0.y);
  o0.z = fmaf(s2, di, b0.z);
  o0.w = fmaf(s3, di, b0.w);
  o1.x = fmaf(s4, di, b1.x);
  o1.y = fmaf(s5, di, b1.y);
  o1.z = fmaf(s6, di, b1.z);
  o1.w = fmaf(s7, di, b1.w);
  if (RELU) {
    o0.x = o0.x > 0.f ? o0.x : 0.f;
    o0.y = o0.y > 0.f ? o0.y : 0.f;
    o0.z = o0.z > 0.f ? o0.z : 0.f;
    o0.w = o0.w > 0.f ? o0.w : 0.f;
    o1.x = o1.x > 0.f ? o1.x : 0.f;
    o1.y = o1.y > 0.f ? o1.y : 0.f;
    o1.z = o1.z > 0.f ? o1.z : 0.f;
    o1.w = o1.w > 0.f ? o1.w : 0.f;
  }
  *(float4*)&Out[(size_t)i * C + c8] = o0;
  *(float4*)&Out[(size_t)i * C + c8 + 4] = o1;
}

// ===========================================================================
// Skinny GEMM, W staged in LDS; fused per-row dinv scale; fp16 output.
// ===========================================================================
template <int K, int NOUT>
__global__ __launch_bounds__(256) void gemm_kernel(const float* __restrict__ X,
                                                   const float* __restrict__ Wm,
                                                   const float* __restrict__ scale,
                                                   __half* __restrict__ Hout, int M) {
  constexpr int RPT = 4;
  constexpr int CT = NOUT / 4;       // col-threads (32 or 16)
  constexpr int RT = 256 / CT;       // row-threads (8 or 16)
  constexpr int BROWS = RT * RPT;    // rows per block (32 or 64)

  __shared__ float Wl[K * NOUT];
  const int tid = threadIdx.x;
  for (int i = tid * 4; i < K * NOUT; i += 256 * 4)
    *(float4*)&Wl[i] = *(const float4*)&Wm[i];
  __syncthreads();

  const int ct = tid % CT;
  const int rt = tid / CT;
  const long long row0 = (long long)blockIdx.x * BROWS + (long long)rt * RPT;

  const float* xr[RPT];
#pragma unroll
  for (int r = 0; r < RPT; ++r) {
    long long rr = row0 + r;
    if (rr > M - 1) rr = M - 1;
    xr[r] = X + rr * K;
  }

  float4 acc[RPT];
#pragma unroll
  for (int r = 0; r < RPT; ++r) acc[r] = make_float4(0.f, 0.f, 0.f, 0.f);

#pragma unroll 4
  for (int k = 0; k < K; k += 4) {
    float4 w0 = *(const float4*)&Wl[(k + 0) * NOUT + ct * 4];
    float4 w1 = *(const float4*)&Wl[(k + 1) * NOUT + ct * 4];
    float4 w2 = *(const float4*)&Wl[(k + 2) * NOUT + ct * 4];
    float4 w3 = *(const float4*)&Wl[(k + 3) * NOUT + ct * 4];
#pragma unroll
    for (int r = 0; r < RPT; ++r) {
      float4 xv = *(const float4*)(xr[r] + k);
      acc[r] = fma4(xv.x, w0, acc[r]);
      acc[r] = fma4(xv.y, w1, acc[r]);
      acc[r] = fma4(xv.z, w2, acc[r]);
      acc[r] = fma4(xv.w, w3, acc[r]);
    }
  }

#pragma unroll
  for (int r = 0; r < RPT; ++r) {
    long long rr = row0 + r;
    if (rr < M) {
      float4 v = acc[r];
      float s = scale[rr];
      __half2 p0 = __float22half2_rn(make_float2(v.x * s, v.y * s));
      __half2 p1 = __float22half2_rn(make_float2(v.z * s, v.w * s));
      __half2* dst = (__half2*)&Hout[rr * NOUT + ct * 4];
      dst[0] = p0;
      dst[1] = p1;
    }
  }
}

// ===========================================================================
// Launch
// ===========================================================================
extern "C" void kernel_launch(void* const* d_in, const int* in_sizes, int n_in,
                              void* d_out, int out_size, void* d_ws, size_t ws_size,
                              hipStream_t stream) {
  const float* x = (const float*)d_in[0];
  const void* eidx = d_in[1];
  const float* W1 = (const float*)d_in[2];
  const float* b1 = (const float*)d_in[3];
  const float* W2 = (const float*)d_in[4];
  const float* b2 = (const float*)d_in[5];
  float* out = (float*)d_out;
  char* ws = (char*)d_ws;

  // Workspace layout (512B-aligned, ~97.2 MB total; harness provides >=110 MB
  // as proven by rounds 2-4 running the large-ws path):
  float* dinv      = (float*)(ws + 0);          //   400,000 B
  int*   row_start = (int*)(ws + 401408);       //   400,004 B
  int*   cursor    = (int*)(ws + 802816);       //   400,000 B  [histogram in]
  int*   flag      = (int*)(ws + 1203200);      //         4 B
  int*   partial   = (int*)(ws + 1203712);      //     1,564 B
  int*   src32     = (int*)(ws + 1205760);      // 6,400,000 B
  int*   dst32     = (int*)(ws + 7606272);      // 6,400,000 B
  int*   csr_src   = (int*)(ws + 14006784);     // 6,400,000 B
  __half* h1       = (__half*)(ws + 20407296);  // 25,600,000 B (fp16 Hs; reused layer 2)
  float* hidden    = (float*)(ws + 46007808);   // 51,200,000 B
  __half* h2 = h1;

  detect_idx_kernel<<<1, 64, 0, stream>>>(eidx, flag);
  zero_int_kernel<<<(NNODES + 255) / 256, 256, 0, stream>>>(cursor, NNODES);
  compress_count_kernel<<<(NEDGES + 255) / 256, 256, 0, stream>>>(eidx, flag, src32, dst32,
                                                                  cursor);
  scan_partial_kernel<<<SCAN_BLOCKS, 256, 0, stream>>>(cursor, partial);
  scan_base_kernel<<<1, 512, 0, stream>>>(partial);
  scan_final_kernel<<<SCAN_BLOCKS, 256, 0, stream>>>(cursor, partial, row_start, cursor, dinv);
  fill_csr_xcd_kernel<<<XCD_COUNT * FILL_CHUNKS, 256, 0, stream>>>(src32, dst32, cursor,
                                                                   csr_src);

  // Layer 1: Hs1 = fp16((x @ W1) * dinv[row]); hidden = relu(di*(Hs1[i]+sum)+b1)
  gemm_kernel<IN_C, HID_C>
      <<<(NNODES + 31) / 32, 256, 0, stream>>>(x, W1, dinv, h1, NNODES);
  gather_kernel<HID_C, true>
      <<<(NNODES * (HID_C / 8) + 255) / 256, 256, 0, stream>>>(row_start, csr_src, dinv,
                                                               h1, b1, hidden);
  // Layer 2: Hs2 = fp16((hidden @ W2) * dinv[row]); out = di*(Hs2[i]+sum)+b2
  gemm_kernel<HID_C, OUT_C>
      <<<(NNODES + 63) / 64, 256, 0, stream>>>(hidden, W2, dinv, h2, NNODES);
  gather_kernel<OUT_C, false>
      <<<(NNODES * (OUT_C / 8) + 255) / 256, 256, 0, stream>>>(row_start, csr_src, dinv,
                                                               h2, b2, out);
}

// Round 6
// 378.603 us; speedup vs baseline: 11.5491x; 1.2308x over previous
//
#include <hip/hip_runtime.h>
#include <hip/hip_fp16.h>

// Problem constants (fixed-size problem)
#define NNODES 100000
#define NEDGES 1600000
#define IN_C   128
#define HID_C  128
#define OUT_C  64

#define SCAN_BLOCKS ((NNODES + 255) / 256)  // 391
#define XCD_COUNT   8
#define XCD_NODES   ((NNODES + XCD_COUNT - 1) / XCD_COUNT)  // 12500
#define FILL_CHUNKS 80
#define EDGES_PER_CHUNK ((NEDGES + FILL_CHUNKS - 1) / FILL_CHUNKS)  // 20000

typedef __attribute__((ext_vector_type(8))) _Float16 half8;
typedef __attribute__((ext_vector_type(4))) _Float16 half4;
typedef __attribute__((ext_vector_type(4))) float floatx4;

// ---------------------------------------------------------------------------
// Index width handling (int64 per reference vs int32 from JAX default)
// ---------------------------------------------------------------------------
__device__ __forceinline__ long long load_idx(const void* p, long long i, int is64) {
  return is64 ? ((const long long*)p)[i] : (long long)((const int*)p)[i];
}

__global__ void detect_idx_kernel(const void* eidx, int* flag) {
  const unsigned* w = (const unsigned*)eidx;
  int lane = threadIdx.x & 63;
  unsigned v = w[2 * lane + 1];
  unsigned long long bad = __ballot(v != 0u);
  if (lane == 0) *flag = (bad == 0ull) ? 1 : 0;
}

// ===========================================================================
// CSR build
// ===========================================================================

__global__ void zero_int_kernel(int* p, int n) {
  int i = blockIdx.x * 256 + threadIdx.x;
  if (i < n) p[i] = 0;
}

__global__ void compress_count_kernel(const void* eidx, const int* flag,
                                      int* __restrict__ src32,
                                      int* __restrict__ dst32,
                                      int* __restrict__ cnt) {
  int e = blockIdx.x * 256 + threadIdx.x;
  if (e < NEDGES) {
    int is64 = *flag;
    int s = (int)load_idx(eidx, e, is64);
    int d = (int)load_idx(eidx, (long long)NEDGES + e, is64);
    src32[e] = s;
    dst32[e] = d;
    atomicAdd(&cnt[d], 1);
  }
}

__global__ __launch_bounds__(256) void scan_partial_kernel(const int* __restrict__ cnt,
                                                           int* __restrict__ partial) {
  __shared__ int red[256];
  int t = threadIdx.x;
  int i = blockIdx.x * 256 + t;
  int v = (i < NNODES) ? cnt[i] : 0;
  red[t] = v;
  __syncthreads();
#pragma unroll
  for (int off = 128; off > 0; off >>= 1) {
    if (t < off) red[t] += red[t + off];
    __syncthreads();
  }
  if (t == 0) partial[blockIdx.x] = red[0];
}

__global__ __launch_bounds__(512) void scan_base_kernel(int* __restrict__ partial) {
  __shared__ int s[512];
  int t = threadIdx.x;
  int v = (t < SCAN_BLOCKS) ? partial[t] : 0;
  s[t] = v;
  __syncthreads();
  for (int off = 1; off < 512; off <<= 1) {
    int other = (t >= off) ? s[t - off] : 0;
    __syncthreads();
    s[t] += other;
    __syncthreads();
  }
  if (t < SCAN_BLOCKS) partial[t] = s[t] - v;  // exclusive base
}

__global__ __launch_bounds__(256) void scan_final_kernel(const int* __restrict__ cnt_in,
                                                         const int* __restrict__ partial,
                                                         int* __restrict__ row_start,
                                                         int* __restrict__ cursor,
                                                         float* __restrict__ dinv) {
  __shared__ int s[256];
  int t = threadIdx.x;
  int i = blockIdx.x * 256 + t;
  int c = (i < NNODES) ? cnt_in[i] : 0;
  s[t] = c;
  __syncthreads();
  int acc = c;
  for (int off = 1; off < 256; off <<= 1) {
    int other = (t >= off) ? s[t - off] : 0;
    __syncthreads();
    acc += other;
    s[t] = acc;
    __syncthreads();
  }
  if (i < NNODES) {
    int rs = partial[blockIdx.x] + acc - c;  // exclusive
    row_start[i] = rs;
    cursor[i] = rs;
    dinv[i] = rsqrtf((float)(c + 1));
    if (i == NNODES - 1) row_start[NNODES] = NEDGES;
  }
}

// XCD-partitioned CSR fill (round-4 win: 16x less write amplification)
__global__ __launch_bounds__(256) void fill_csr_xcd_kernel(const int* __restrict__ src32,
                                                           const int* __restrict__ dst32,
                                                           int* __restrict__ cursor,
                                                           int* __restrict__ csr_src) {
  const int xcd = blockIdx.x & (XCD_COUNT - 1);
  const int chunk = blockIdx.x >> 3;
  const int lo = xcd * XCD_NODES;
  const int e_beg = chunk * EDGES_PER_CHUNK;
  const int e_end = min(e_beg + EDGES_PER_CHUNK, NEDGES);
  for (int e = e_beg + threadIdx.x; e < e_end; e += 256) {
    int d = dst32[e];
    int s = src32[e];
    if ((unsigned)(d - lo) < (unsigned)XCD_NODES) {
      int pos = atomicAdd(&cursor[d], 1);
      csr_src[pos] = s;
    }
  }
}

// ---------------------------------------------------------------------------
// Gather aggregation over PRE-SCALED fp16 rows Hs[i] = h[i]*dinv[i]:
//   Out[i] = act( dinv[i] * (Hs[i] + sum_j Hs[csr_src[j]]) + bias )
// OUT16: write fp16 (hidden); else fp32 (final output).
// ---------------------------------------------------------------------------
struct F8 {
  float x0, x1, x2, x3, x4, x5, x6, x7;
};

__device__ __forceinline__ void add_h8(F8& a, const __half* p) {
  int4 r = *(const int4*)p;  // 8 halves
  const __half2* h = (const __half2*)&r;
  float2 f0 = __half22float2(h[0]);
  float2 f1 = __half22float2(h[1]);
  float2 f2 = __half22float2(h[2]);
  float2 f3 = __half22float2(h[3]);
  a.x0 += f0.x; a.x1 += f0.y; a.x2 += f1.x; a.x3 += f1.y;
  a.x4 += f2.x; a.x5 += f2.y; a.x6 += f3.x; a.x7 += f3.y;
}

template <int C, bool RELU, bool OUT16>
__global__ __launch_bounds__(256) void gather_kernel(const int* __restrict__ row_start,
                                                     const int* __restrict__ csr_src,
                                                     const float* __restrict__ dinv,
                                                     const __half* __restrict__ Hs,
                                                     const float* __restrict__ bias,
                                                     void* __restrict__ OutPtr) {
  constexpr int TPN = C / 8;  // threads per node (16 or 8)
  int gid = blockIdx.x * 256 + threadIdx.x;
  int i = gid / TPN;
  int c8 = (gid % TPN) * 8;
  if (i >= NNODES) return;

  const float di = dinv[i];
  const int beg = row_start[i];
  const int end = row_start[i + 1];

  F8 a0 = {}, a1 = {}, a2 = {}, a3 = {};
  add_h8(a0, &Hs[(size_t)i * C + c8]);  // self term (pre-scaled)

  int j = beg;
  for (; j + 8 <= end; j += 8) {
    int s0 = csr_src[j + 0], s1 = csr_src[j + 1], s2 = csr_src[j + 2], s3 = csr_src[j + 3];
    int s4 = csr_src[j + 4], s5 = csr_src[j + 5], s6 = csr_src[j + 6], s7 = csr_src[j + 7];
    add_h8(a0, &Hs[(size_t)s0 * C + c8]);
    add_h8(a1, &Hs[(size_t)s1 * C + c8]);
    add_h8(a2, &Hs[(size_t)s2 * C + c8]);
    add_h8(a3, &Hs[(size_t)s3 * C + c8]);
    add_h8(a0, &Hs[(size_t)s4 * C + c8]);
    add_h8(a1, &Hs[(size_t)s5 * C + c8]);
    add_h8(a2, &Hs[(size_t)s6 * C + c8]);
    add_h8(a3, &Hs[(size_t)s7 * C + c8]);
  }
  for (; j + 2 <= end; j += 2) {
    int s0 = csr_src[j + 0], s1 = csr_src[j + 1];
    add_h8(a0, &Hs[(size_t)s0 * C + c8]);
    add_h8(a1, &Hs[(size_t)s1 * C + c8]);
  }
  if (j < end) {
    add_h8(a0, &Hs[(size_t)csr_src[j] * C + c8]);
  }

  float s0 = a0.x0 + a1.x0 + a2.x0 + a3.x0;
  float s1 = a0.x1 + a1.x1 + a2.x1 + a3.x1;
  float s2 = a0.x2 + a1.x2 + a2.x2 + a3.x2;
  float s3 = a0.x3 + a1.x3 + a2.x3 + a3.x3;
  float s4 = a0.x4 + a1.x4 + a2.x4 + a3.x4;
  float s5 = a0.x5 + a1.x5 + a2.x5 + a3.x5;
  float s6 = a0.x6 + a1.x6 + a2.x6 + a3.x6;
  float s7 = a0.x7 + a1.x7 + a2.x7 + a3.x7;

  float4 b0 = *(const float4*)&bias[c8];
  float4 b1 = *(const float4*)&bias[c8 + 4];
  float o0 = fmaf(s0, di, b0.x);
  float o1 = fmaf(s1, di, b0.y);
  float o2 = fmaf(s2, di, b0.z);
  float o3 = fmaf(s3, di, b0.w);
  float o4 = fmaf(s4, di, b1.x);
  float o5 = fmaf(s5, di, b1.y);
  float o6 = fmaf(s6, di, b1.z);
  float o7 = fmaf(s7, di, b1.w);
  if (RELU) {
    o0 = o0 > 0.f ? o0 : 0.f;
    o1 = o1 > 0.f ? o1 : 0.f;
    o2 = o2 > 0.f ? o2 : 0.f;
    o3 = o3 > 0.f ? o3 : 0.f;
    o4 = o4 > 0.f ? o4 : 0.f;
    o5 = o5 > 0.f ? o5 : 0.f;
    o6 = o6 > 0.f ? o6 : 0.f;
    o7 = o7 > 0.f ? o7 : 0.f;
  }
  if (OUT16) {
    half8 hv = {(_Float16)o0, (_Float16)o1, (_Float16)o2, (_Float16)o3,
                (_Float16)o4, (_Float16)o5, (_Float16)o6, (_Float16)o7};
    *(half8*)((_Float16*)OutPtr + (size_t)i * C + c8) = hv;
  } else {
    float* Out = (float*)OutPtr;
    float4 v0 = make_float4(o0, o1, o2, o3);
    float4 v1 = make_float4(o4, o5, o6, o7);
    *(float4*)&Out[(size_t)i * C + c8] = v0;
    *(float4*)&Out[(size_t)i * C + c8 + 4] = v1;
  }
}

// ===========================================================================
// MFMA fp16 GEMM: Hout[M,N] = fp16( (X[M,K] @ W[K,N]) * scale[row] )
// 64-row M-tile per block, 4 waves x 16 rows. W in LDS transposed [n][k],
// A-tile in LDS [m][k], both fp16 with +8-half row pad (2-way bank aliasing,
// free per m136). Fragment layouts (HW-verified m89/m91/m120):
//   A: m=lane&15, k=8*(lane>>4)+j ; B: n=lane&15, same k ;
//   D: row=4*(lane>>4)+reg, col=lane&15.
// ===========================================================================
template <int K, int N, bool A_F16>
__global__ __launch_bounds__(256) void mfma_gemm_kernel(const void* __restrict__ Xv,
                                                        const float* __restrict__ Wm,
                                                        const float* __restrict__ scale,
                                                        _Float16* __restrict__ Hout,
                                                        int M) {
  constexpr int KP = K + 8;  // padded row stride in halves (136)
  __shared__ alignas(16) _Float16 Alds[64 * KP];
  __shared__ alignas(16) _Float16 Wlds[N * KP];

  const int tid = threadIdx.x;
  const int row0 = blockIdx.x * 64;

  // ---- stage W (KxN fp32 row-major) -> Wlds[n][k] fp16, 4x4 transpose ----
  constexpr int TILES = (K / 4) * (N / 4);
  for (int tile = tid; tile < TILES; tile += 256) {
    int kt = tile / (N / 4);
    int nt = tile % (N / 4);
    const float* wp = &Wm[(4 * kt) * N + 4 * nt];
    float4 r0 = *(const float4*)(wp);
    float4 r1 = *(const float4*)(wp + N);
    float4 r2 = *(const float4*)(wp + 2 * N);
    float4 r3 = *(const float4*)(wp + 3 * N);
    half4 c0 = {(_Float16)r0.x, (_Float16)r1.x, (_Float16)r2.x, (_Float16)r3.x};
    half4 c1 = {(_Float16)r0.y, (_Float16)r1.y, (_Float16)r2.y, (_Float16)r3.y};
    half4 c2 = {(_Float16)r0.z, (_Float16)r1.z, (_Float16)r2.z, (_Float16)r3.z};
    half4 c3 = {(_Float16)r0.w, (_Float16)r1.w, (_Float16)r2.w, (_Float16)r3.w};
    *(half4*)&Wlds[(4 * nt + 0) * KP + 4 * kt] = c0;
    *(half4*)&Wlds[(4 * nt + 1) * KP + 4 * kt] = c1;
    *(half4*)&Wlds[(4 * nt + 2) * KP + 4 * kt] = c2;
    *(half4*)&Wlds[(4 * nt + 3) * KP + 4 * kt] = c3;
  }

  // ---- stage A tile (64 x K) -> Alds fp16 ----
  if (A_F16) {
    const _Float16* Xh = (const _Float16*)Xv;
    constexpr int H8PR = K / 8;  // half8 per row (16)
    constexpr int TOT = 64 * H8PR;
    for (int idx = tid; idx < TOT; idx += 256) {
      int lr = idx / H8PR;
      int c8 = (idx % H8PR) * 8;
      int gr = row0 + lr;
      if (gr > M - 1) gr = M - 1;
      int4 v = *(const int4*)&Xh[(size_t)gr * K + c8];
      *(int4*)&Alds[lr * KP + c8] = v;
    }
  } else {
    const float* Xf = (const float*)Xv;
    constexpr int F4PR = K / 4;  // float4 per row (32)
    constexpr int TOT = 64 * F4PR;
    for (int idx = tid; idx < TOT; idx += 256) {
      int lr = idx / F4PR;
      int c4 = (idx % F4PR) * 4;
      int gr = row0 + lr;
      if (gr > M - 1) gr = M - 1;
      float4 v = *(const float4*)&Xf[(size_t)gr * K + c4];
      half4 h = {(_Float16)v.x, (_Float16)v.y, (_Float16)v.z, (_Float16)v.w};
      *(half4*)&Alds[lr * KP + c4] = h;
    }
  }
  __syncthreads();

  // ---- compute ----
  const int w = tid >> 6;
  const int lane = tid & 63;
  const int g = lane >> 4;
  const int mi = lane & 15;
  constexpr int NT = N / 16;

  floatx4 acc[NT];
#pragma unroll
  for (int t = 0; t < NT; ++t) acc[t] = (floatx4){0.f, 0.f, 0.f, 0.f};

  const _Float16* arow = &Alds[(w * 16 + mi) * KP];
#pragma unroll
  for (int ks = 0; ks < K / 32; ++ks) {
    half8 a = *(const half8*)(arow + ks * 32 + g * 8);
#pragma unroll
    for (int t = 0; t < NT; ++t) {
      half8 b = *(const half8*)&Wlds[(t * 16 + mi) * KP + ks * 32 + g * 8];
      acc[t] = __builtin_amdgcn_mfma_f32_16x16x32_f16(a, b, acc[t], 0, 0, 0);
    }
  }

  // ---- epilogue: scale by dinv[row], store fp16 ----
#pragma unroll
  for (int r = 0; r < 4; ++r) {
    int grow = row0 + w * 16 + 4 * g + r;
    if (grow < M) {
      float s = scale[grow];
      _Float16* orow = Hout + (size_t)grow * N + mi;
#pragma unroll
      for (int t = 0; t < NT; ++t) orow[t * 16] = (_Float16)(acc[t][r] * s);
    }
  }
}

// ===========================================================================
// Launch
// ===========================================================================
extern "C" void kernel_launch(void* const* d_in, const int* in_sizes, int n_in,
                              void* d_out, int out_size, void* d_ws, size_t ws_size,
                              hipStream_t stream) {
  const float* x = (const float*)d_in[0];
  const void* eidx = d_in[1];
  const float* W1 = (const float*)d_in[2];
  const float* b1 = (const float*)d_in[3];
  const float* W2 = (const float*)d_in[4];
  const float* b2 = (const float*)d_in[5];
  float* out = (float*)d_out;
  char* ws = (char*)d_ws;

  // Workspace layout (512B-aligned, ~72 MB; harness provides >=110 MB):
  float* dinv      = (float*)(ws + 0);          //   400,000 B
  int*   row_start = (int*)(ws + 401408);       //   400,004 B
  int*   cursor    = (int*)(ws + 802816);       //   400,000 B  [histogram in]
  int*   flag      = (int*)(ws + 1203200);      //         4 B
  int*   partial   = (int*)(ws + 1203712);      //     1,564 B
  int*   src32     = (int*)(ws + 1205760);      // 6,400,000 B
  int*   dst32     = (int*)(ws + 7606272);      // 6,400,000 B
  int*   csr_src   = (int*)(ws + 14006784);     // 6,400,000 B
  _Float16* h1     = (_Float16*)(ws + 20407296);// 25,600,000 B (fp16 Hs; reused layer 2)
  _Float16* hidden = (_Float16*)(ws + 46007808);// 25,600,000 B (fp16)
  _Float16* h2 = h1;

  detect_idx_kernel<<<1, 64, 0, stream>>>(eidx, flag);
  zero_int_kernel<<<(NNODES + 255) / 256, 256, 0, stream>>>(cursor, NNODES);
  compress_count_kernel<<<(NEDGES + 255) / 256, 256, 0, stream>>>(eidx, flag, src32, dst32,
                                                                  cursor);
  scan_partial_kernel<<<SCAN_BLOCKS, 256, 0, stream>>>(cursor, partial);
  scan_base_kernel<<<1, 512, 0, stream>>>(partial);
  scan_final_kernel<<<SCAN_BLOCKS, 256, 0, stream>>>(cursor, partial, row_start, cursor, dinv);
  fill_csr_xcd_kernel<<<XCD_COUNT * FILL_CHUNKS, 256, 0, stream>>>(src32, dst32, cursor,
                                                                   csr_src);

  const int GB = (NNODES + 63) / 64;  // 1563 M-tiles

  // Layer 1: Hs1 = fp16((x @ W1) * dinv); hidden = fp16(relu(di*(Hs1[i]+sum)+b1))
  mfma_gemm_kernel<IN_C, HID_C, false>
      <<<GB, 256, 0, stream>>>(x, W1, dinv, h1, NNODES);
  gather_kernel<HID_C, true, true>
      <<<(NNODES * (HID_C / 8) + 255) / 256, 256, 0, stream>>>(row_start, csr_src, dinv,
                                                               (const __half*)h1, b1, hidden);
  // Layer 2: Hs2 = fp16((hidden @ W2) * dinv); out = di*(Hs2[i]+sum)+b2 (fp32)
  mfma_gemm_kernel<HID_C, OUT_C, true>
      <<<GB, 256, 0, stream>>>(hidden, W2, dinv, h2, NNODES);
  gather_kernel<OUT_C, false, false>
      <<<(NNODES * (OUT_C / 8) + 255) / 256, 256, 0, stream>>>(row_start, csr_src, dinv,
                                                               (const __half*)h2, b2, out);
}